// Round 24
// baseline (104.365 us; speedup 1.0000x reference)
//
#include <hip/hip_runtime.h>
#include <hip/hip_bf16.h>
#include <math.h>

namespace {
constexpr int kB = 2, kT = 2048, kD = 1024, kH = 16, kHD = 64;
}

typedef __attribute__((ext_vector_type(8))) short short8;
typedef __attribute__((ext_vector_type(4))) float f32x4;
typedef __attribute__((ext_vector_type(16))) float f32x16;

#if __has_builtin(__builtin_amdgcn_exp2f)
#define EXP2F(x) __builtin_amdgcn_exp2f(x)
#else
#define EXP2F(x) __expf((x) * 0.6931471805599453f)
#endif

__device__ __forceinline__ ushort f2bf(float f) {
  union { float f; uint u; } c; c.f = f;
  uint u = c.u + 0x7FFFu + ((c.u >> 16) & 1u);
  return (ushort)(u >> 16);
}

__device__ __forceinline__ float bf2f(ushort u) {
  union { uint u; float f; } c; c.u = ((uint)u) << 16; return c.f;
}

// HW packed f32->bf16x2 (RNE). T12: no builtin on gfx950 -- inline asm.
__device__ __forceinline__ uint pack_bf2(float a, float b) {
  uint r;
  asm("v_cvt_pk_bf16_f32 %0, %1, %2" : "=v"(r) : "v"(a), "v"(b));
  return r;
}

__device__ __forceinline__ void gload_lds16(const void* g, void* l) {
  __builtin_amdgcn_global_load_lds(
      (const __attribute__((address_space(1))) void*)g,
      (__attribute__((address_space(3))) void*)l, 16, 0, 0);
}

// ---------------------------------------------------------------------------
// Layouts:
//  Q   : row-major (bh, t, hd)        -- coalesced proj writes; loaded once
//  K_f : fragment-major               -- contiguous attn staging (hot loop)
//  V_f : fragment-major               -- contiguous attn staging (hot loop)
//  Op  : row-major [ks(2)][bh][t][hd]
// LESSONS (R8/R14/R19/R21): attn cannot trade registers for occupancy in
// either direction; 32-key chunk / 16KB dbuf / (256,4) is the fixed point.
// R24: proj switched to 2-phase loop at BK=32 with 64KB LDS -> 2 blocks/CU
// (was 1 at 128KB); attn's proven stage->compute->barrier pattern.
// ---------------------------------------------------------------------------

// ---------------------------------------------------------------------------
// Kernel 0: convert x + 4 weight matrices f32 -> bf16.  8 elems/thread.
// ---------------------------------------------------------------------------
__global__ __launch_bounds__(256) void cvt_kernel(
    const float* __restrict__ x, const float* __restrict__ w0,
    const float* __restrict__ w1, const float* __restrict__ w2,
    const float* __restrict__ w3, ushort* __restrict__ out)
{
  const size_t g = (size_t)blockIdx.x * 256 + threadIdx.x;
  const size_t e = g * 8;
  const float* src; size_t rel;
  if (e < ((size_t)1 << 22)) { src = x; rel = e; }
  else {
    size_t e2 = e - ((size_t)1 << 22);
    int wi = (int)(e2 >> 20);
    src = wi == 0 ? w0 : wi == 1 ? w1 : wi == 2 ? w2 : w3;
    rel = e2 & (((size_t)1 << 20) - 1);
  }
  float4 v0 = *reinterpret_cast<const float4*>(src + rel);
  float4 v1 = *reinterpret_cast<const float4*>(src + rel + 4);
  union { ushort u[8]; short8 s8; } o;
  o.u[0] = f2bf(v0.x); o.u[1] = f2bf(v0.y); o.u[2] = f2bf(v0.z); o.u[3] = f2bf(v0.w);
  o.u[4] = f2bf(v1.x); o.u[5] = f2bf(v1.y); o.u[6] = f2bf(v1.z); o.u[7] = f2bf(v1.w);
  *reinterpret_cast<short8*>(out + e) = o.s8;
}

// ---------------------------------------------------------------------------
// Kernel 1: 256x256 MFMA GEMM, R24 2-phase loop (BK=32, 64KB LDS,
// 2 blocks/CU).  8 waves (2Mx4N).  Per K-half: stage next buffer (4x
// gload_lds 16B/thread), compute 32 MFMA from current, one barrier.
// Epilogue: mat 0 -> Q row-major prescaled; mat 1 -> K_f; mat 2 -> V_f;
// mat 3 -> g bf16.
// ---------------------------------------------------------------------------
__device__ __forceinline__ void stage_half(
    const ushort* __restrict__ src, int row0, int kcol0,
    ushort* ldsbase, int wid, int lane)
{
#pragma unroll
  for (int part = 0; part < 2; ++part) {
    const int c = part * 512 + wid * 64 + lane;
    const int x = c * 16;                        // LDS byte offset in half-tile
    const int o = x ^ (((x >> 7) & 3) << 4);     // inverse-swizzled logical byte
    const int r = o >> 6;                        // logical row (0..255)
    const int cb = (o & 63) >> 1;                // logical col element (0..31)
    gload_lds16(src + (size_t)(row0 + r) * kD + kcol0 + cb, ldsbase + (x >> 1));
  }
}

__device__ __forceinline__ short8 read_frag(const ushort* half, int r, int lg) {
  const int slot = lg ^ ((r >> 1) & 3);          // swizzled 16B slot
  return *reinterpret_cast<const short8*>(&half[r * 32 + slot * 8]);
}

__global__ __launch_bounds__(512) void proj_mfma_kernel(
    const ushort* __restrict__ Xb, const ushort* __restrict__ Wb,
    const float* __restrict__ bq, const float* __restrict__ bk,
    const float* __restrict__ bv, const float* __restrict__ bg,
    ushort* __restrict__ qo, ushort* __restrict__ ko,
    ushort* __restrict__ vt, ushort* __restrict__ go)
{
  const int mat = blockIdx.z;
  const ushort* Wm = Wb + (size_t)mat * 1024 * 1024;
  const float* bias = mat == 0 ? bq : mat == 1 ? bk : mat == 2 ? bv : bg;
  const int m0 = blockIdx.x * 256;
  const int n0g = blockIdx.y * 256;
  const int tid = threadIdx.x;
  const int wid = tid >> 6, lane = tid & 63;
  const int wr = wid >> 2, wc = wid & 3;
  const int wrow = wr * 128, wcol = wc * 64;
  const int lr = lane & 15, lg = lane >> 4;

  // 2 buffers x [A 8192 ush (16KB)][B 8192 ush (16KB)] = 64 KB
  __shared__ ushort lds[32768];

  f32x4 acc[8][4];
#pragma unroll
  for (int i = 0; i < 8; ++i)
#pragma unroll
    for (int j = 0; j < 4; ++j) acc[i][j] = (f32x4){0.f, 0.f, 0.f, 0.f};

#define STAGE32(bu, kh) do {                                                \
    stage_half(Xb, m0,  (kh) * 32, &lds[(bu) * 16384], wid, lane);          \
    stage_half(Wm, n0g, (kh) * 32, &lds[(bu) * 16384 + 8192], wid, lane);   \
  } while (0)

  STAGE32(0, 0);
  __syncthreads();

#pragma unroll 1
  for (int kh = 0; kh < 32; ++kh) {
    const int cur = kh & 1;
    if (kh + 1 < 32) STAGE32(cur ^ 1, kh + 1);
    const ushort* Ah = &lds[cur * 16384];
    const ushort* Bh = &lds[cur * 16384 + 8192];
    short8 bfr[4];
#pragma unroll
    for (int ni = 0; ni < 4; ++ni)
      bfr[ni] = read_frag(Bh, wcol + ni * 16 + lr, lg);
    __builtin_amdgcn_s_setprio(1);
#pragma unroll
    for (int mb = 0; mb < 2; ++mb) {
      short8 af[4];
#pragma unroll
      for (int m2 = 0; m2 < 4; ++m2)
        af[m2] = read_frag(Ah, wrow + (mb * 4 + m2) * 16 + lr, lg);
#pragma unroll
      for (int m2 = 0; m2 < 4; ++m2)
#pragma unroll
        for (int ni = 0; ni < 4; ++ni)
          acc[mb * 4 + m2][ni] = __builtin_amdgcn_mfma_f32_16x16x32_bf16(
              af[m2], bfr[ni], acc[mb * 4 + m2][ni], 0, 0, 0);
    }
    __builtin_amdgcn_s_setprio(0);
    __syncthreads();   // drains vmcnt (next buffer ready) + LDS reads done
  }

#undef STAGE32

  // Q pre-scale: softmax wants exp2(qk * log2e/8); fold into Q here.
  const float vsc = (mat == 0) ? 0.18033688f : 1.0f;

  // Epilogue: C row = m0 + wrow + mi*16 + 4*lg + r, col = n0g + wcol + ni*16 + lr
#pragma unroll
  for (int mi = 0; mi < 8; ++mi) {
    const int mbase = m0 + wrow + mi * 16 + 4 * lg;
    const int b = mbase >> 11, t0r = mbase & (kT - 1);
#pragma unroll
    for (int ni = 0; ni < 4; ++ni) {
      const int n = n0g + wcol + ni * 16 + lr;
      const float bn = bias[n];
      if (mat == 3) {
#pragma unroll
        for (int r = 0; r < 4; ++r)
          go[(size_t)(mbase + r) * kD + n] = f2bf(acc[mi][ni][r] + bn);
      } else if (mat == 2) {
        // V_f: tokens t0r..t0r+3 (4-aligned), fixed hd -> contiguous ushort4
        const int h = n >> 6, hd = n & 63;
        const int bh2 = b * kH + h;
        const int nh = hd >> 5, lv = hd & 31;
        const int kc = t0r >> 5, kk0 = t0r & 31;
        const int jf = kk0 >> 4, hi2 = (kk0 >> 3) & 1, jj0 = kk0 & 7;
        const int lane2 = lv + hi2 * 32;
        const size_t off =
            (((((size_t)bh2 * 64 + kc) * 2 + nh) * 2 + jf) * 64 + lane2) * 8 + jj0;
        ushort4 u;
        u.x = f2bf(acc[mi][ni][0] + bn); u.y = f2bf(acc[mi][ni][1] + bn);
        u.z = f2bf(acc[mi][ni][2] + bn); u.w = f2bf(acc[mi][ni][3] + bn);
        *reinterpret_cast<ushort4*>(&vt[off]) = u;
      } else if (mat == 1) {
        // K_f fragment-major (scatter; hot-loop staging contiguity wins)
        const int h = n >> 6, hd = n & 63;
        const int bh2 = b * kH + h;
        const int hk = hd >> 4, hi2 = (hd >> 3) & 1, jj = hd & 7;
#pragma unroll
        for (int r = 0; r < 4; ++r) {
          const int t = t0r + r;
          const int kc = t >> 5, kk = t & 31;
          const size_t off =
              ((((size_t)bh2 * 64 + kc) * 4 + hk) * 64 + kk + hi2 * 32) * 8 + jj;
          ko[off] = f2bf(acc[mi][ni][r] + bn);
        }
      } else {
        // Q row-major (bh, t, hd), prescaled: coalesced stores
        const int h = n >> 6, hd = n & 63;
        const int bh2 = b * kH + h;
#pragma unroll
        for (int r = 0; r < 4; ++r)
          qo[((size_t)bh2 * kT + t0r + r) * kHD + hd] =
              f2bf((acc[mi][ni][r] + bn) * vsc);
      }
    }
  }
}

// ---------------------------------------------------------------------------
// Kernel 2: MFMA flash attention, swapped-operand 32x32x16, K-split x2.
// 1024 blocks = exactly 4/CU; each block covers 1024 keys (32 iters).
// K/V staged once per block into double-buffered 16 KB LDS (contiguous
// tid*16B gather); row-major Op epilogue.  (R18/R20/R22 verified.)
// ---------------------------------------------------------------------------
__global__ __launch_bounds__(256, 4) void attn_mfma32_kernel(
    const ushort* __restrict__ Qrm, const ushort* __restrict__ Kf,
    const ushort* __restrict__ Vf, ushort* __restrict__ Op,
    float* __restrict__ lsumP)
{
  const int bid = blockIdx.x;           // 1024
  const int xcd = bid & 7;
  const int j = bid >> 3;               // 0..127
  const int bh = xcd * 4 + (j >> 5);    // 4 bh per XCD
  const int rem = j & 31;
  const int qt = rem & 15;              // q-tile (128 rows)
  const int ks = rem >> 4;              // key-split 0..1
  const int tid = threadIdx.x, w = tid >> 6, lane = tid & 63;
  const int lq = lane & 31;
  const int hi = lane >> 5;

  // [K 4KB][V 4KB] per buffer, double-buffered = 16 KB
  __shared__ ushort kvA[4096];
  __shared__ ushort kvB[4096];

  const int q0 = qt * 128 + w * 32;
  // Q (row-major, pre-scaled): one-time strided load
  short8 aq[4];
#pragma unroll
  for (int hk = 0; hk < 4; ++hk)
    aq[hk] = *reinterpret_cast<const short8*>(
        &Qrm[((size_t)bh * kT + q0 + lq) * kHD + hk * 16 + hi * 8]);

  f32x16 oacc[2];
#pragma unroll
  for (int nh = 0; nh < 2; ++nh)
#pragma unroll
    for (int r = 0; r < 16; ++r) oacc[nh][r] = 0.f;
  float lsum = 0.f;

  const ushort* kbase = Kf + ((size_t)bh * 64 + ks * 32) * 2048;
  const ushort* vbase = Vf + ((size_t)bh * 64 + ks * 32) * 2048;

#define STAGE_KV(dst, t) do {                                               \
    gload_lds16(kbase + (size_t)(t) * 2048 + tid * 8, &dst[tid * 8]);       \
    gload_lds16(vbase + (size_t)(t) * 2048 + tid * 8, &dst[2048 + tid * 8]);\
  } while (0)

#define COMPUTE_KV(buf) do {                                                \
    short8 kf_[4];                                                          \
    _Pragma("unroll")                                                       \
    for (int hk = 0; hk < 4; ++hk)                                          \
      kf_[hk] = *reinterpret_cast<const short8*>(&buf[(hk * 64 + lane) * 8]);\
    short8 vf[2][2];                                                        \
    _Pragma("unroll")                                                       \
    for (int nh = 0; nh < 2; ++nh)                                          \
      _Pragma("unroll")                                                     \
      for (int jf = 0; jf < 2; ++jf)                                        \
        vf[nh][jf] = *reinterpret_cast<const short8*>(                      \
            &buf[2048 + ((nh * 2 + jf) * 64 + lane) * 8]);                  \
    f32x16 s;                                                               \
    _Pragma("unroll")                                                       \
    for (int r = 0; r < 16; ++r) s[r] = 0.f;                                \
    __builtin_amdgcn_s_setprio(1);                                          \
    _Pragma("unroll")                                                       \
    for (int hk = 0; hk < 4; ++hk)                                          \
      s = __builtin_amdgcn_mfma_f32_32x32x16_bf16(kf_[hk], aq[hk], s, 0, 0, 0);\
    __builtin_amdgcn_s_setprio(0);                                          \
    float p[16];                                                            \
    _Pragma("unroll")                                                       \
    for (int r = 0; r < 16; ++r) p[r] = EXP2F(s[r]);                        \
    float t0 = 0.f, t1 = 0.f;                                               \
    _Pragma("unroll")                                                       \
    for (int r = 0; r < 16; r += 2) { t0 += p[r]; t1 += p[r + 1]; }         \
    lsum += t0 + t1;                                                        \
    uint pk[8];                                                             \
    _Pragma("unroll")                                                       \
    for (int m = 0; m < 8; ++m) pk[m] = pack_bf2(p[2 * m], p[2 * m + 1]);   \
    union { uint u[4]; short8 s8; } fa0, fa1;                               \
    {                                                                       \
      auto s0 = __builtin_amdgcn_permlane32_swap(pk[0], pk[2], false, false);\
      auto s1 = __builtin_amdgcn_permlane32_swap(pk[1], pk[3], false, false);\
      auto s2 = __builtin_amdgcn_permlane32_swap(pk[4], pk[6], false, false);\
      auto s3 = __builtin_amdgcn_permlane32_swap(pk[5], pk[7], false, false);\
      fa0.u[0] = s0[0]; fa0.u[2] = s0[1];                                   \
      fa0.u[1] = s1[0]; fa0.u[3] = s1[1];                                   \
      fa1.u[0] = s2[0]; fa1.u[2] = s2[1];                                   \
      fa1.u[1] = s3[0]; fa1.u[3] = s3[1];                                   \
    }                                                                       \
    __builtin_amdgcn_s_setprio(1);                                          \
    oacc[0] = __builtin_amdgcn_mfma_f32_32x32x16_bf16(vf[0][0], fa0.s8, oacc[0], 0, 0, 0);\
    oacc[0] = __builtin_amdgcn_mfma_f32_32x32x16_bf16(vf[0][1], fa1.s8, oacc[0], 0, 0, 0);\
    oacc[1] = __builtin_amdgcn_mfma_f32_32x32x16_bf16(vf[1][0], fa0.s8, oacc[1], 0, 0, 0);\
    oacc[1] = __builtin_amdgcn_mfma_f32_32x32x16_bf16(vf[1][1], fa1.s8, oacc[1], 0, 0, 0);\
    __builtin_amdgcn_s_setprio(0);                                          \
  } while (0)

  STAGE_KV(kvA, 0);
  __syncthreads();

#pragma unroll 1
  for (int kt = 0; kt < 32; kt += 2) {
    if (kt + 1 < 32) STAGE_KV(kvB, kt + 1);
    COMPUTE_KV(kvA);
    __syncthreads();
    if (kt + 2 < 32) STAGE_KV(kvA, kt + 2);
    COMPUTE_KV(kvB);
    __syncthreads();
  }

#undef STAGE_KV
#undef COMPUTE_KV

  lsum += __shfl_xor(lsum, 32);

  const size_t prow = (((size_t)ks * 32 + bh) * kT + (q0 + lq)) * kHD;
#pragma unroll
  for (int nh = 0; nh < 2; ++nh)
#pragma unroll
    for (int g2 = 0; g2 < 4; ++g2) {
      ushort4 u;
      u.x = f2bf(oacc[nh][4 * g2 + 0]);
      u.y = f2bf(oacc[nh][4 * g2 + 1]);
      u.z = f2bf(oacc[nh][4 * g2 + 2]);
      u.w = f2bf(oacc[nh][4 * g2 + 3]);
      *reinterpret_cast<ushort4*>(&Op[prow + nh * 32 + 8 * g2 + 4 * hi]) = u;
    }
  if (hi == 0)
    lsumP[((size_t)ks * 32 + bh) * kT + q0 + lq] = lsum;
}

// ---------------------------------------------------------------------------
// Kernel 3: combine K-split partials (x2) + gate + GroupNorm.  Vectorized:
// 16 lanes per (b,t,h) group, ushort4/float4 per thread, 4-step shuffle
// reduce.  Row-major Op read.
// ---------------------------------------------------------------------------
__global__ __launch_bounds__(256) void gn_kernel(
    const ushort* __restrict__ gb, const ushort* __restrict__ Op,
    const float* __restrict__ lsumP,
    const float* __restrict__ gamma, const float* __restrict__ beta,
    float* __restrict__ out)
{
  const int tid = threadIdx.x;
  const int grp = blockIdx.x * 16 + (tid >> 4);   // bt*16 + h
  const int l16 = tid & 15;
  const int bt = grp >> 4, h = grp & 15;
  const int b = bt >> 11, t = bt & (kT - 1);
  const int bh = b * kH + h;
  const int c0 = l16 * 4;                          // 4 channels per thread

  float l = 0.f;
  float ov[4] = {0.f, 0.f, 0.f, 0.f};
#pragma unroll
  for (int ks = 0; ks < 2; ++ks) {
    const size_t base = ((size_t)ks * 32 + bh) * kT + t;
    ushort4 o4 = *reinterpret_cast<const ushort4*>(&Op[base * kHD + c0]);
    ov[0] += bf2f(o4.x); ov[1] += bf2f(o4.y);
    ov[2] += bf2f(o4.z); ov[3] += bf2f(o4.w);
    l += lsumP[base];
  }
  const float inv_l = 1.f / l;
  ushort4 g4 = *reinterpret_cast<const ushort4*>(&gb[(size_t)bt * kD + h * kHD + c0]);
  float y[4];
  y[0] = bf2f(g4.x) * ov[0] * inv_l; y[1] = bf2f(g4.y) * ov[1] * inv_l;
  y[2] = bf2f(g4.z) * ov[2] * inv_l; y[3] = bf2f(g4.w) * ov[3] * inv_l;

  float s = y[0] + y[1] + y[2] + y[3];
  float ss = y[0]*y[0] + y[1]*y[1] + y[2]*y[2] + y[3]*y[3];
#pragma unroll
  for (int off = 8; off; off >>= 1) {
    s  += __shfl_xor(s, off);
    ss += __shfl_xor(ss, off);
  }
  const float mean = s * (1.f / 64.f);
  const float var  = ss * (1.f / 64.f) - mean * mean;
  const float inv  = rsqrtf(var + 1e-5f);

  float4 gm = *reinterpret_cast<const float4*>(&gamma[h * kHD + c0]);
  float4 bt4 = *reinterpret_cast<const float4*>(&beta[h * kHD + c0]);
  float4 o;
  o.x = (y[0] - mean) * inv * gm.x + bt4.x;
  o.y = (y[1] - mean) * inv * gm.y + bt4.y;
  o.z = (y[2] - mean) * inv * gm.z + bt4.z;
  o.w = (y[3] - mean) * inv * gm.w + bt4.w;
  *reinterpret_cast<float4*>(&out[(size_t)bt * kD + h * kHD + c0]) = o;
}

// ---------------------------------------------------------------------------
extern "C" void kernel_launch(void* const* d_in, const int* in_sizes, int n_in,
                              void* d_out, int out_size, void* d_ws, size_t ws_size,
                              hipStream_t stream) {
  const float* x     = (const float*)d_in[0];
  const float* wq    = (const float*)d_in[1];
  const float* bq    = (const float*)d_in[2];
  const float* wk    = (const float*)d_in[3];
  const float* bk    = (const float*)d_in[4];
  const float* wv    = (const float*)d_in[5];
  const float* bv    = (const float*)d_in[6];
  const float* wg    = (const float*)d_in[7];
  const float* bg    = (const float*)d_in[8];
  const float* gamma = (const float*)d_in[9];
  const float* beta  = (const float*)d_in[10];

  // ws: [cb 8388608][Q 4194304][K_f 4194304][V_f 4194304][gb 4194304][Op 16777216]
  // lsumP (f32, 262144) aliases cb (cb dead after proj; lsumP used by attn/gn).
  ushort* cb  = (ushort*)d_ws;
  ushort* qb  = cb + (size_t)8388608;
  ushort* kb  = qb + (size_t)4194304;
  ushort* vtb = kb + (size_t)4194304;
  ushort* gb  = vtb + (size_t)4194304;
  ushort* Op  = gb + (size_t)4194304;
  float*  lsumP = (float*)cb;
  float*  out = (float*)d_out;

  const ushort* xb = cb;
  const ushort* wb = cb + (size_t)4194304;

  cvt_kernel<<<4096, 256, 0, stream>>>(x, wq, wk, wv, wg, cb);
  proj_mfma_kernel<<<dim3(16, 4, 4), 512, 0, stream>>>(
      xb, wb, bq, bk, bv, bg, qb, kb, vtb, gb);
  attn_mfma32_kernel<<<1024, 256, 0, stream>>>(qb, kb, vtb, Op, lsumP);
  gn_kernel<<<4096, 256, 0, stream>>>(gb, Op, lsumP, gamma, beta, out);
}

// Round 25
// 101.400 us; speedup vs baseline: 1.0292x; 1.0292x over previous
//
#include <hip/hip_runtime.h>
#include <hip/hip_bf16.h>
#include <math.h>

namespace {
constexpr int kB = 2, kT = 2048, kD = 1024, kH = 16, kHD = 64;
}

typedef __attribute__((ext_vector_type(8))) short short8;
typedef __attribute__((ext_vector_type(4))) float f32x4;
typedef __attribute__((ext_vector_type(16))) float f32x16;

#if __has_builtin(__builtin_amdgcn_exp2f)
#define EXP2F(x) __builtin_amdgcn_exp2f(x)
#else
#define EXP2F(x) __expf((x) * 0.6931471805599453f)
#endif

__device__ __forceinline__ ushort f2bf(float f) {
  union { float f; uint u; } c; c.f = f;
  uint u = c.u + 0x7FFFu + ((c.u >> 16) & 1u);
  return (ushort)(u >> 16);
}

__device__ __forceinline__ float bf2f(ushort u) {
  union { uint u; float f; } c; c.u = ((uint)u) << 16; return c.f;
}

// HW packed f32->bf16x2 (RNE). T12: no builtin on gfx950 -- inline asm.
__device__ __forceinline__ uint pack_bf2(float a, float b) {
  uint r;
  asm("v_cvt_pk_bf16_f32 %0, %1, %2" : "=v"(r) : "v"(a), "v"(b));
  return r;
}

__device__ __forceinline__ void gload_lds16(const void* g, void* l) {
  __builtin_amdgcn_global_load_lds(
      (const __attribute__((address_space(1))) void*)g,
      (__attribute__((address_space(3))) void*)l, 16, 0, 0);
}

// ---------------------------------------------------------------------------
// FINAL CONFIG (R23, best measured 101.6us):
//  Q   : row-major (bh, t, hd)        -- coalesced proj writes; loaded once
//  K_f : fragment-major               -- contiguous attn staging (hot loop)
//  V_f : fragment-major               -- contiguous attn staging (hot loop)
//  Op  : row-major [ks(2)][bh][t][hd]
// Mapped-and-rejected space: attn 64-key macro (spills, R14/R19), attn
// 8 waves/EU (spills, R8/R21), lane-major Op (R16), proj 2-phase/64KB
// (grid-limited 1 block/CU anyway, R24), proj K_f direct scatter (== LDS
// route, R22/R23).  Both big kernels are latency-bound fixed points at
// ~30% MfmaUtil; every register/occupancy/LDS trade measured negative.
// ---------------------------------------------------------------------------

// ---------------------------------------------------------------------------
// Kernel 0: convert x + 4 weight matrices f32 -> bf16.  8 elems/thread.
// ---------------------------------------------------------------------------
__global__ __launch_bounds__(256) void cvt_kernel(
    const float* __restrict__ x, const float* __restrict__ w0,
    const float* __restrict__ w1, const float* __restrict__ w2,
    const float* __restrict__ w3, ushort* __restrict__ out)
{
  const size_t g = (size_t)blockIdx.x * 256 + threadIdx.x;
  const size_t e = g * 8;
  const float* src; size_t rel;
  if (e < ((size_t)1 << 22)) { src = x; rel = e; }
  else {
    size_t e2 = e - ((size_t)1 << 22);
    int wi = (int)(e2 >> 20);
    src = wi == 0 ? w0 : wi == 1 ? w1 : wi == 2 ? w2 : w3;
    rel = e2 & (((size_t)1 << 20) - 1);
  }
  float4 v0 = *reinterpret_cast<const float4*>(src + rel);
  float4 v1 = *reinterpret_cast<const float4*>(src + rel + 4);
  union { ushort u[8]; short8 s8; } o;
  o.u[0] = f2bf(v0.x); o.u[1] = f2bf(v0.y); o.u[2] = f2bf(v0.z); o.u[3] = f2bf(v0.w);
  o.u[4] = f2bf(v1.x); o.u[5] = f2bf(v1.y); o.u[6] = f2bf(v1.z); o.u[7] = f2bf(v1.w);
  *reinterpret_cast<short8*>(out + e) = o.s8;
}

// ---------------------------------------------------------------------------
// Kernel 1: 256x256x(K=64) 8-phase MFMA GEMM (T2+T3/T4+T5).
// Epilogue: mat 0 -> Q row-major prescaled; mat 1 -> K_f (via LDS);
// mat 2 -> V_f; mat 3 -> g bf16.
// ---------------------------------------------------------------------------
__device__ __forceinline__ void stage_half(
    const ushort* __restrict__ src, int row0, int kcol0,
    ushort* ldsbase, int wid, int lane)
{
#pragma unroll
  for (int part = 0; part < 2; ++part) {
    const int c = part * 512 + wid * 64 + lane;
    const int x = c * 16;                        // LDS byte offset in half-tile
    const int o = x ^ (((x >> 7) & 3) << 4);     // inverse-swizzled logical byte
    const int r = o >> 6;                        // logical row (0..255)
    const int cb = (o & 63) >> 1;                // logical col element (0..31)
    gload_lds16(src + (size_t)(row0 + r) * kD + kcol0 + cb, ldsbase + (x >> 1));
  }
}

__device__ __forceinline__ short8 read_frag(const ushort* half, int r, int lg) {
  const int slot = lg ^ ((r >> 1) & 3);          // swizzled 16B slot
  return *reinterpret_cast<const short8*>(&half[r * 32 + slot * 8]);
}

#define PH_BAR() do { asm volatile("" ::: "memory"); \
  __builtin_amdgcn_s_barrier(); asm volatile("" ::: "memory"); } while (0)

__global__ __launch_bounds__(512, 2) void proj_mfma_kernel(
    const ushort* __restrict__ Xb, const ushort* __restrict__ Wb,
    const float* __restrict__ bq, const float* __restrict__ bk,
    const float* __restrict__ bv, const float* __restrict__ bg,
    ushort* __restrict__ qo, ushort* __restrict__ ko,
    ushort* __restrict__ vt, ushort* __restrict__ go)
{
  const int mat = blockIdx.z;
  const ushort* Wm = Wb + (size_t)mat * 1024 * 1024;
  const float* bias = mat == 0 ? bq : mat == 1 ? bk : mat == 2 ? bv : bg;
  const int m0 = blockIdx.x * 256;
  const int n0g = blockIdx.y * 256;
  const int tid = threadIdx.x;
  const int wid = tid >> 6, lane = tid & 63;
  const int wr = wid >> 2, wc = wid & 3;
  const int wrow = wr * 128, wcol = wc * 64;
  const int lr = lane & 15, lg = lane >> 4;

  // [buf(2)][A/B(2)][khalf(2)][16KB half-tile] = 128 KB
  __shared__ ushort lds[65536];

  f32x4 acc[8][4];
#pragma unroll
  for (int i = 0; i < 8; ++i)
#pragma unroll
    for (int j = 0; j < 4; ++j) acc[i][j] = (f32x4){0.f, 0.f, 0.f, 0.f};

  short8 bfr[4];

#define STAGE_A(bu, h, kt) stage_half(Xb, m0,  (kt) * 64 + (h) * 32, \
    &lds[(bu) * 32768 + (h) * 8192], wid, lane)
#define STAGE_B(bu, h, kt) stage_half(Wm, n0g, (kt) * 64 + (h) * 32, \
    &lds[(bu) * 32768 + 16384 + (h) * 8192], wid, lane)

#define PHASE(bu, h, MB, READB, STAGE_STMT, DOVM)                          \
  {                                                                        \
    const ushort* Ah = &lds[(bu) * 32768 + (h) * 8192];                    \
    const ushort* Bh = &lds[(bu) * 32768 + 16384 + (h) * 8192];            \
    short8 af[4];                                                          \
    af[0] = read_frag(Ah, wrow + (MB + 0) * 16 + lr, lg);                  \
    af[1] = read_frag(Ah, wrow + (MB + 1) * 16 + lr, lg);                  \
    af[2] = read_frag(Ah, wrow + (MB + 2) * 16 + lr, lg);                  \
    af[3] = read_frag(Ah, wrow + (MB + 3) * 16 + lr, lg);                  \
    if (READB) {                                                           \
      bfr[0] = read_frag(Bh, wcol + 0 * 16 + lr, lg);                      \
      bfr[1] = read_frag(Bh, wcol + 1 * 16 + lr, lg);                      \
      bfr[2] = read_frag(Bh, wcol + 2 * 16 + lr, lg);                      \
      bfr[3] = read_frag(Bh, wcol + 3 * 16 + lr, lg);                      \
    }                                                                      \
    STAGE_STMT;                                                            \
    PH_BAR();                                                              \
    __builtin_amdgcn_s_setprio(1);                                         \
    _Pragma("unroll")                                                      \
    for (int m2 = 0; m2 < 4; ++m2)                                         \
      _Pragma("unroll")                                                    \
      for (int ni = 0; ni < 4; ++ni)                                       \
        acc[(MB) + m2][ni] = __builtin_amdgcn_mfma_f32_16x16x32_bf16(      \
            af[m2], bfr[ni], acc[(MB) + m2][ni], 0, 0, 0);                 \
    __builtin_amdgcn_s_setprio(0);                                         \
    if (DOVM) asm volatile("s_waitcnt vmcnt(4)" ::: "memory");             \
    PH_BAR();                                                              \
  }

  // Prologue: tile0 fully + tile1 khalf0; drain tile0 (12 issued, keep 4).
  STAGE_A(0, 0, 0); STAGE_B(0, 0, 0);
  STAGE_A(0, 1, 0); STAGE_B(0, 1, 0);
  STAGE_A(1, 0, 1); STAGE_B(1, 0, 1);
  asm volatile("s_waitcnt vmcnt(4)" ::: "memory");
  PH_BAR();

#pragma unroll 1
  for (int it = 0; it < 8; ++it) {
    const int ta = 2 * it, tb = 2 * it + 1;
    const int tn0 = (ta + 2) & 15;   // wraps on last iter: dummy-safe stage
    const int tn1 = (tb + 2) & 15;
    PHASE(0, 0, 0, 1, (STAGE_A(1, 1, tb)),  0)   // P1
    PHASE(0, 0, 4, 0, (STAGE_B(1, 1, tb)),  0)   // P2
    PHASE(0, 1, 0, 1, (STAGE_A(0, 0, tn0)), 0)   // P3
    PHASE(0, 1, 4, 0, (STAGE_B(0, 0, tn0)), 1)   // P4 + vmcnt(4)
    PHASE(1, 0, 0, 1, (STAGE_A(0, 1, tn0)), 0)   // P5
    PHASE(1, 0, 4, 0, (STAGE_B(0, 1, tn0)), 0)   // P6
    PHASE(1, 1, 0, 1, (STAGE_A(1, 0, tn1)), 0)   // P7
    PHASE(1, 1, 4, 0, (STAGE_B(1, 0, tn1)), 1)   // P8 + vmcnt(4)
  }

#undef PHASE
#undef STAGE_A
#undef STAGE_B

  // Q pre-scale: softmax wants exp2(qk * log2e/8); fold into Q here.
  const float vsc = (mat == 0) ? 0.18033688f : 1.0f;

  // Epilogue: C row = m0 + wrow + mi*16 + 4*lg + r, col = n0g + wcol + ni*16 + lr
#pragma unroll
  for (int mi = 0; mi < 8; ++mi) {
    const int mbase = m0 + wrow + mi * 16 + 4 * lg;
    const int b = mbase >> 11, t0r = mbase & (kT - 1);
#pragma unroll
    for (int ni = 0; ni < 4; ++ni) {
      const int n = n0g + wcol + ni * 16 + lr;
      const float bn = bias[n];
      if (mat == 3) {
#pragma unroll
        for (int r = 0; r < 4; ++r)
          go[(size_t)(mbase + r) * kD + n] = f2bf(acc[mi][ni][r] + bn);
      } else if (mat == 2) {
        // V_f: tokens t0r..t0r+3 (4-aligned), fixed hd -> contiguous ushort4
        const int h = n >> 6, hd = n & 63;
        const int bh2 = b * kH + h;
        const int nh = hd >> 5, lv = hd & 31;
        const int kc = t0r >> 5, kk0 = t0r & 31;
        const int jf = kk0 >> 4, hi2 = (kk0 >> 3) & 1, jj0 = kk0 & 7;
        const int lane2 = lv + hi2 * 32;
        const size_t off =
            (((((size_t)bh2 * 64 + kc) * 2 + nh) * 2 + jf) * 64 + lane2) * 8 + jj0;
        ushort4 u;
        u.x = f2bf(acc[mi][ni][0] + bn); u.y = f2bf(acc[mi][ni][1] + bn);
        u.z = f2bf(acc[mi][ni][2] + bn); u.w = f2bf(acc[mi][ni][3] + bn);
        *reinterpret_cast<ushort4*>(&vt[off]) = u;
      } else if (mat == 1) {
        // K_f: stash bf16 into LDS at tile-local K_f offset;
        // vectorized coalesced flush after the barrier below.
        const int nl = n - n0g;                  // 0..255
        const int hloc = nl >> 6, hd = nl & 63;
        const int hk = hd >> 4, hi2 = (hd >> 3) & 1, jj = hd & 7;
        const int tl0 = mbase - m0;              // 0..255
#pragma unroll
        for (int r = 0; r < 4; ++r) {
          const int tl = tl0 + r;
          const int off = (((hloc * 8 + (tl >> 5)) * 4 + hk) * 64
                           + (tl & 31) + hi2 * 32) * 8 + jj;
          lds[off] = f2bf(acc[mi][ni][r] + bn);
        }
      } else {
        // Q row-major (bh, t, hd), prescaled: coalesced stores
        const int h = n >> 6, hd = n & 63;
        const int bh2 = b * kH + h;
#pragma unroll
        for (int r = 0; r < 4; ++r)
          qo[((size_t)bh2 * kT + t0r + r) * kHD + hd] =
              f2bf((acc[mi][ni][r] + bn) * vsc);
      }
    }
  }

  if (mat == 1) {
    __syncthreads();   // full lgkmcnt drain: all LDS stashes visible
    const int b0 = m0 >> 11;
    const int kc0 = (m0 & (kT - 1)) >> 5;        // multiple of 8
    const int bh20 = b0 * kH + (n0g >> 6);       // first of 4 heads
    // flush: 16 x (ds_read_b128 + coalesced global dwordx4) per thread.
#pragma unroll
    for (int i = 0; i < 16; ++i) {
      const int Lu = (i * 512 + tid) * 8;        // ushort offset in tile
      const int hloc = Lu >> 14;
      const int rem = Lu & 16383;
      const size_t goff = (size_t)(bh20 + hloc) * 131072
                          + (size_t)kc0 * 2048 + rem;
      *reinterpret_cast<short8*>(&ko[goff]) =
          *reinterpret_cast<const short8*>(&lds[Lu]);
    }
  }
}

// ---------------------------------------------------------------------------
// Kernel 2: MFMA flash attention, swapped-operand 32x32x16, K-split x2.
// 1024 blocks = exactly 4/CU; each block covers 1024 keys (32 iters).
// K/V staged once per block into double-buffered 16 KB LDS (contiguous
// tid*16B gather); row-major Op epilogue.
// ---------------------------------------------------------------------------
__global__ __launch_bounds__(256, 4) void attn_mfma32_kernel(
    const ushort* __restrict__ Qrm, const ushort* __restrict__ Kf,
    const ushort* __restrict__ Vf, ushort* __restrict__ Op,
    float* __restrict__ lsumP)
{
  const int bid = blockIdx.x;           // 1024
  const int xcd = bid & 7;
  const int j = bid >> 3;               // 0..127
  const int bh = xcd * 4 + (j >> 5);    // 4 bh per XCD
  const int rem = j & 31;
  const int qt = rem & 15;              // q-tile (128 rows)
  const int ks = rem >> 4;              // key-split 0..1
  const int tid = threadIdx.x, w = tid >> 6, lane = tid & 63;
  const int lq = lane & 31;
  const int hi = lane >> 5;

  // [K 4KB][V 4KB] per buffer, double-buffered = 16 KB
  __shared__ ushort kvA[4096];
  __shared__ ushort kvB[4096];

  const int q0 = qt * 128 + w * 32;
  // Q (row-major, pre-scaled): one-time strided load
  short8 aq[4];
#pragma unroll
  for (int hk = 0; hk < 4; ++hk)
    aq[hk] = *reinterpret_cast<const short8*>(
        &Qrm[((size_t)bh * kT + q0 + lq) * kHD + hk * 16 + hi * 8]);

  f32x16 oacc[2];
#pragma unroll
  for (int nh = 0; nh < 2; ++nh)
#pragma unroll
    for (int r = 0; r < 16; ++r) oacc[nh][r] = 0.f;
  float lsum = 0.f;

  const ushort* kbase = Kf + ((size_t)bh * 64 + ks * 32) * 2048;
  const ushort* vbase = Vf + ((size_t)bh * 64 + ks * 32) * 2048;

#define STAGE_KV(dst, t) do {                                               \
    gload_lds16(kbase + (size_t)(t) * 2048 + tid * 8, &dst[tid * 8]);       \
    gload_lds16(vbase + (size_t)(t) * 2048 + tid * 8, &dst[2048 + tid * 8]);\
  } while (0)

#define COMPUTE_KV(buf) do {                                                \
    short8 kf_[4];                                                          \
    _Pragma("unroll")                                                       \
    for (int hk = 0; hk < 4; ++hk)                                          \
      kf_[hk] = *reinterpret_cast<const short8*>(&buf[(hk * 64 + lane) * 8]);\
    short8 vf[2][2];                                                        \
    _Pragma("unroll")                                                       \
    for (int nh = 0; nh < 2; ++nh)                                          \
      _Pragma("unroll")                                                     \
      for (int jf = 0; jf < 2; ++jf)                                        \
        vf[nh][jf] = *reinterpret_cast<const short8*>(                      \
            &buf[2048 + ((nh * 2 + jf) * 64 + lane) * 8]);                  \
    f32x16 s;                                                               \
    _Pragma("unroll")                                                       \
    for (int r = 0; r < 16; ++r) s[r] = 0.f;                                \
    __builtin_amdgcn_s_setprio(1);                                          \
    _Pragma("unroll")                                                       \
    for (int hk = 0; hk < 4; ++hk)                                          \
      s = __builtin_amdgcn_mfma_f32_32x32x16_bf16(kf_[hk], aq[hk], s, 0, 0, 0);\
    __builtin_amdgcn_s_setprio(0);                                          \
    float p[16];                                                            \
    _Pragma("unroll")                                                       \
    for (int r = 0; r < 16; ++r) p[r] = EXP2F(s[r]);                        \
    float t0 = 0.f, t1 = 0.f;                                               \
    _Pragma("unroll")                                                       \
    for (int r = 0; r < 16; r += 2) { t0 += p[r]; t1 += p[r + 1]; }         \
    lsum += t0 + t1;                                                        \
    uint pk[8];                                                             \
    _Pragma("unroll")                                                       \
    for (int m = 0; m < 8; ++m) pk[m] = pack_bf2(p[2 * m], p[2 * m + 1]);   \
    union { uint u[4]; short8 s8; } fa0, fa1;                               \
    {                                                                       \
      auto s0 = __builtin_amdgcn_permlane32_swap(pk[0], pk[2], false, false);\
      auto s1 = __builtin_amdgcn_permlane32_swap(pk[1], pk[3], false, false);\
      auto s2 = __builtin_amdgcn_permlane32_swap(pk[4], pk[6], false, false);\
      auto s3 = __builtin_amdgcn_permlane32_swap(pk[5], pk[7], false, false);\
      fa0.u[0] = s0[0]; fa0.u[2] = s0[1];                                   \
      fa0.u[1] = s1[0]; fa0.u[3] = s1[1];                                   \
      fa1.u[0] = s2[0]; fa1.u[2] = s2[1];                                   \
      fa1.u[1] = s3[0]; fa1.u[3] = s3[1];                                   \
    }                                                                       \
    __builtin_amdgcn_s_setprio(1);                                          \
    oacc[0] = __builtin_amdgcn_mfma_f32_32x32x16_bf16(vf[0][0], fa0.s8, oacc[0], 0, 0, 0);\
    oacc[0] = __builtin_amdgcn_mfma_f32_32x32x16_bf16(vf[0][1], fa1.s8, oacc[0], 0, 0, 0);\
    oacc[1] = __builtin_amdgcn_mfma_f32_32x32x16_bf16(vf[1][0], fa0.s8, oacc[1], 0, 0, 0);\
    oacc[1] = __builtin_amdgcn_mfma_f32_32x32x16_bf16(vf[1][1], fa1.s8, oacc[1], 0, 0, 0);\
    __builtin_amdgcn_s_setprio(0);                                          \
  } while (0)

  STAGE_KV(kvA, 0);
  __syncthreads();

#pragma unroll 1
  for (int kt = 0; kt < 32; kt += 2) {
    if (kt + 1 < 32) STAGE_KV(kvB, kt + 1);
    COMPUTE_KV(kvA);
    __syncthreads();
    if (kt + 2 < 32) STAGE_KV(kvA, kt + 2);
    COMPUTE_KV(kvB);
    __syncthreads();
  }

#undef STAGE_KV
#undef COMPUTE_KV

  lsum += __shfl_xor(lsum, 32);

  const size_t prow = (((size_t)ks * 32 + bh) * kT + (q0 + lq)) * kHD;
#pragma unroll
  for (int nh = 0; nh < 2; ++nh)
#pragma unroll
    for (int g2 = 0; g2 < 4; ++g2) {
      ushort4 u;
      u.x = f2bf(oacc[nh][4 * g2 + 0]);
      u.y = f2bf(oacc[nh][4 * g2 + 1]);
      u.z = f2bf(oacc[nh][4 * g2 + 2]);
      u.w = f2bf(oacc[nh][4 * g2 + 3]);
      *reinterpret_cast<ushort4*>(&Op[prow + nh * 32 + 8 * g2 + 4 * hi]) = u;
    }
  if (hi == 0)
    lsumP[((size_t)ks * 32 + bh) * kT + q0 + lq] = lsum;
}

// ---------------------------------------------------------------------------
// Kernel 3: combine K-split partials (x2) + gate + GroupNorm.  Vectorized:
// 16 lanes per (b,t,h) group, ushort4/float4 per thread, 4-step shuffle
// reduce.  Row-major Op read.
// ---------------------------------------------------------------------------
__global__ __launch_bounds__(256) void gn_kernel(
    const ushort* __restrict__ gb, const ushort* __restrict__ Op,
    const float* __restrict__ lsumP,
    const float* __restrict__ gamma, const float* __restrict__ beta,
    float* __restrict__ out)
{
  const int tid = threadIdx.x;
  const int grp = blockIdx.x * 16 + (tid >> 4);   // bt*16 + h
  const int l16 = tid & 15;
  const int bt = grp >> 4, h = grp & 15;
  const int b = bt >> 11, t = bt & (kT - 1);
  const int bh = b * kH + h;
  const int c0 = l16 * 4;                          // 4 channels per thread

  float l = 0.f;
  float ov[4] = {0.f, 0.f, 0.f, 0.f};
#pragma unroll
  for (int ks = 0; ks < 2; ++ks) {
    const size_t base = ((size_t)ks * 32 + bh) * kT + t;
    ushort4 o4 = *reinterpret_cast<const ushort4*>(&Op[base * kHD + c0]);
    ov[0] += bf2f(o4.x); ov[1] += bf2f(o4.y);
    ov[2] += bf2f(o4.z); ov[3] += bf2f(o4.w);
    l += lsumP[base];
  }
  const float inv_l = 1.f / l;
  ushort4 g4 = *reinterpret_cast<const ushort4*>(&gb[(size_t)bt * kD + h * kHD + c0]);
  float y[4];
  y[0] = bf2f(g4.x) * ov[0] * inv_l; y[1] = bf2f(g4.y) * ov[1] * inv_l;
  y[2] = bf2f(g4.z) * ov[2] * inv_l; y[3] = bf2f(g4.w) * ov[3] * inv_l;

  float s = y[0] + y[1] + y[2] + y[3];
  float ss = y[0]*y[0] + y[1]*y[1] + y[2]*y[2] + y[3]*y[3];
#pragma unroll
  for (int off = 8; off; off >>= 1) {
    s  += __shfl_xor(s, off);
    ss += __shfl_xor(ss, off);
  }
  const float mean = s * (1.f / 64.f);
  const float var  = ss * (1.f / 64.f) - mean * mean;
  const float inv  = rsqrtf(var + 1e-5f);

  float4 gm = *reinterpret_cast<const float4*>(&gamma[h * kHD + c0]);
  float4 bt4 = *reinterpret_cast<const float4*>(&beta[h * kHD + c0]);
  float4 o;
  o.x = (y[0] - mean) * inv * gm.x + bt4.x;
  o.y = (y[1] - mean) * inv * gm.y + bt4.y;
  o.z = (y[2] - mean) * inv * gm.z + bt4.z;
  o.w = (y[3] - mean) * inv * gm.w + bt4.w;
  *reinterpret_cast<float4*>(&out[(size_t)bt * kD + h * kHD + c0]) = o;
}

// ---------------------------------------------------------------------------
extern "C" void kernel_launch(void* const* d_in, const int* in_sizes, int n_in,
                              void* d_out, int out_size, void* d_ws, size_t ws_size,
                              hipStream_t stream) {
  const float* x     = (const float*)d_in[0];
  const float* wq    = (const float*)d_in[1];
  const float* bq    = (const float*)d_in[2];
  const float* wk    = (const float*)d_in[3];
  const float* bk    = (const float*)d_in[4];
  const float* wv    = (const float*)d_in[5];
  const float* bv    = (const float*)d_in[6];
  const float* wg    = (const float*)d_in[7];
  const float* bg    = (const float*)d_in[8];
  const float* gamma = (const float*)d_in[9];
  const float* beta  = (const float*)d_in[10];

  // ws: [cb 8388608][Q 4194304][K_f 4194304][V_f 4194304][gb 4194304][Op 16777216]
  // lsumP (f32, 262144) aliases cb (cb dead after proj; lsumP used by attn/gn).
  ushort* cb  = (ushort*)d_ws;
  ushort* qb  = cb + (size_t)8388608;
  ushort* kb  = qb + (size_t)4194304;
  ushort* vtb = kb + (size_t)4194304;
  ushort* gb  = vtb + (size_t)4194304;
  ushort* Op  = gb + (size_t)4194304;
  float*  lsumP = (float*)cb;
  float*  out = (float*)d_out;

  const ushort* xb = cb;
  const ushort* wb = cb + (size_t)4194304;

  cvt_kernel<<<4096, 256, 0, stream>>>(x, wq, wk, wv, wg, cb);
  proj_mfma_kernel<<<dim3(16, 4, 4), 512, 0, stream>>>(
      xb, wb, bq, bk, bv, bg, qb, kb, vtb, gb);
  attn_mfma32_kernel<<<1024, 256, 0, stream>>>(qb, kb, vtb, Op, lsumP);
  gn_kernel<<<4096, 256, 0, stream>>>(gb, Op, lsumP, gamma, beta, out);
}